// Round 12
// baseline (27.217 us; speedup 1.0000x reference)
//
#include <hip/hip_runtime.h>

#define NC 1024
#define NS 32
#define DD 512
#define MARGIN 0.3f

// Kernel 1: 512 blocks, 512 threads (8 waves); block b processes classes
// 2b and 2b+1, software-pipelined: class-(2b+1) loads are issued right
// after class-2b's squared-diffs, so 2b's reduce/barrier/hinge tail runs
// with 128 KB of next-class loads in flight. 512 blocks = 2 blocks/CU =
// whole grid co-resident (zero mid-kernel dispatch ramps).
//
// Lane mapping (R11, proven): wave w owns float4 columns [w*16, w*16+16);
// lane l = g*16+c16 owns rows s = 4j+g (j<8) of column col4 = w*16+c16.
// Anchor folds intra-wave via shfl_xor(16,32) -- no barrier, no LDS.
//
// Codegen rules (R3-R8): literal loop bounds only (SROA); NO atomics of any
// spelling; separate reduce kernel; asm memory fence to pin load placement.
__global__ __launch_bounds__(512) void ccl_two_class(const float* __restrict__ emb,
                                                     float* __restrict__ cls) {
    const int b = blockIdx.x;
    const int t = threadIdx.x;
    const int w = t >> 6;
    const int l = t & 63;
    const int g = l >> 4;
    const int col4 = (w << 4) + (l & 15);
    const int roff = DD / 4;

    const float4* base0 = (const float4*)(emb + (size_t)(2 * b) * (2 * NS * DD));
    const float4* base1 = base0 + (2 * NS * DD) / 4;

    __shared__ float s_ap0[8][4][8], s_nd0[8][4][8];
    __shared__ float s_ap1[8][4][8], s_nd1[8][4][8];

#define BSTEP(arr, m, half)                                        \
    {                                                              \
        _Pragma("unroll")                                          \
        for (int i = 0; i < (half); ++i) {                         \
            float lo = arr[i], hi = arr[i + (half)];               \
            float send = (l & (m)) ? lo : hi;                      \
            float recv = __shfl_xor(send, (m));                    \
            arr[i] = (l & (m)) ? (hi + recv) : (lo + recv);        \
        }                                                          \
    }

    // ================= class 0 (= 2b): load + anchor + sqdiff =============
    float4 p[8], n[8];
#pragma unroll
    for (int j = 0; j < 8; ++j) p[j] = base0[(4 * j + g) * roff + col4];
#pragma unroll
    for (int j = 0; j < 8; ++j) n[j] = base0[NS * roff + (4 * j + g) * roff + col4];

    float4 a = p[0];
#pragma unroll
    for (int j = 1; j < 8; ++j) {
        a.x += p[j].x; a.y += p[j].y; a.z += p[j].z; a.w += p[j].w;
    }
    a.x += __shfl_xor(a.x, 16); a.y += __shfl_xor(a.y, 16);
    a.z += __shfl_xor(a.z, 16); a.w += __shfl_xor(a.w, 16);
    a.x += __shfl_xor(a.x, 32); a.y += __shfl_xor(a.y, 32);
    a.z += __shfl_xor(a.z, 32); a.w += __shfl_xor(a.w, 32);
    a.x *= (1.f / NS); a.y *= (1.f / NS); a.z *= (1.f / NS); a.w *= (1.f / NS);

    float apc[8], ndc[8];
#pragma unroll
    for (int j = 0; j < 8; ++j) {
        float dx = p[j].x - a.x, dy = p[j].y - a.y, dz = p[j].z - a.z, dw = p[j].w - a.w;
        apc[j] = dx * dx + dy * dy + dz * dz + dw * dw;
        dx = n[j].x - a.x; dy = n[j].y - a.y; dz = n[j].z - a.z; dw = n[j].w - a.w;
        ndc[j] = dx * dx + dy * dy + dz * dz + dw * dw;
    }

    // ============ issue class-1 loads NOW (p/n are dead; fence stops hoist)
    asm volatile("" ::: "memory");
    float4 q[8], mm[8];
#pragma unroll
    for (int j = 0; j < 8; ++j) q[j] = base1[(4 * j + g) * roff + col4];
#pragma unroll
    for (int j = 0; j < 8; ++j) mm[j] = base1[NS * roff + (4 * j + g) * roff + col4];

    // ================= class 0: butterfly + LDS write =====================
    BSTEP(apc, 1, 4) BSTEP(apc, 2, 2) BSTEP(apc, 4, 1)
    BSTEP(ndc, 1, 4) BSTEP(ndc, 2, 2) BSTEP(ndc, 4, 1)
    {
        float rap = apc[0] + __shfl_xor(apc[0], 8);
        float rnd = ndc[0] + __shfl_xor(ndc[0], 8);
        if ((l & 8) == 0) {
            const int jm = ((l & 1) << 2) | (l & 2) | ((l & 4) >> 2);
            s_ap0[w][g][jm] = rap;
            s_nd0[w][g][jm] = rnd;
        }
    }
    __syncthreads();

    // ================= class 1: anchor + sqdiff + butterfly ===============
    float4 a1 = q[0];
#pragma unroll
    for (int j = 1; j < 8; ++j) {
        a1.x += q[j].x; a1.y += q[j].y; a1.z += q[j].z; a1.w += q[j].w;
    }
    a1.x += __shfl_xor(a1.x, 16); a1.y += __shfl_xor(a1.y, 16);
    a1.z += __shfl_xor(a1.z, 16); a1.w += __shfl_xor(a1.w, 16);
    a1.x += __shfl_xor(a1.x, 32); a1.y += __shfl_xor(a1.y, 32);
    a1.z += __shfl_xor(a1.z, 32); a1.w += __shfl_xor(a1.w, 32);
    a1.x *= (1.f / NS); a1.y *= (1.f / NS); a1.z *= (1.f / NS); a1.w *= (1.f / NS);

    float apd[8], nde[8];
#pragma unroll
    for (int j = 0; j < 8; ++j) {
        float dx = q[j].x - a1.x, dy = q[j].y - a1.y, dz = q[j].z - a1.z, dw = q[j].w - a1.w;
        apd[j] = dx * dx + dy * dy + dz * dz + dw * dw;
        dx = mm[j].x - a1.x; dy = mm[j].y - a1.y; dz = mm[j].z - a1.z; dw = mm[j].w - a1.w;
        nde[j] = dx * dx + dy * dy + dz * dz + dw * dw;
    }
    BSTEP(apd, 1, 4) BSTEP(apd, 2, 2) BSTEP(apd, 4, 1)
    BSTEP(nde, 1, 4) BSTEP(nde, 2, 2) BSTEP(nde, 4, 1)
    {
        float rap = apd[0] + __shfl_xor(apd[0], 8);
        float rnd = nde[0] + __shfl_xor(nde[0], 8);
        if ((l & 8) == 0) {
            const int jm = ((l & 1) << 2) | (l & 2) | ((l & 4) >> 2);
            s_ap1[w][g][jm] = rap;
            s_nd1[w][g][jm] = rnd;
        }
    }

    // ================= class-0 tail (wave 0, buf0 is stable post-barrier) =
    if (t < NS) {
        const int sg = t & 3, sj = t >> 2;
        float ap = 0.f, nd = 0.f;
#pragma unroll
        for (int k = 0; k < 8; ++k) { ap += s_ap0[k][sg][sj]; nd += s_nd0[k][sg][sj]; }
        float an = nd;
#pragma unroll
        for (int m = 1; m < 32; m <<= 1) an = fminf(an, __shfl_xor(an, m));
        float hl = fmaxf(ap - an + MARGIN, 0.f);
#pragma unroll
        for (int m = 1; m < 32; m <<= 1) hl += __shfl_xor(hl, m);
        if (t == 0) cls[2 * b] = hl;
    }
    __syncthreads();

    // ================= class-1 tail =======================================
    if (t < NS) {
        const int sg = t & 3, sj = t >> 2;
        float ap = 0.f, nd = 0.f;
#pragma unroll
        for (int k = 0; k < 8; ++k) { ap += s_ap1[k][sg][sj]; nd += s_nd1[k][sg][sj]; }
        float an = nd;
#pragma unroll
        for (int m = 1; m < 32; m <<= 1) an = fminf(an, __shfl_xor(an, m));
        float hl = fmaxf(ap - an + MARGIN, 0.f);
#pragma unroll
        for (int m = 1; m < 32; m <<= 1) hl += __shfl_xor(hl, m);
        if (t == 0) cls[2 * b + 1] = hl;
    }
#undef BSTEP
}

// Kernel 2: single-wave deterministic mean of the 1024 class losses.
__global__ __launch_bounds__(64) void ccl_reduce(const float* __restrict__ class_loss,
                                                 float* __restrict__ out) {
    const int t = threadIdx.x;
    const float4* v4 = (const float4*)class_loss;  // 256 float4
    float4 x0 = v4[t], x1 = v4[t + 64], x2 = v4[t + 128], x3 = v4[t + 192];
    float v = (x0.x + x0.y + x0.z + x0.w) + (x1.x + x1.y + x1.z + x1.w) +
              (x2.x + x2.y + x2.z + x2.w) + (x3.x + x3.y + x3.z + x3.w);
#pragma unroll
    for (int m = 1; m < 64; m <<= 1) v += __shfl_xor(v, m);
    if (t == 0) out[0] = v * (1.f / NC);
}

extern "C" void kernel_launch(void* const* d_in, const int* in_sizes, int n_in,
                              void* d_out, int out_size, void* d_ws, size_t ws_size,
                              hipStream_t stream) {
    const float* emb = (const float*)d_in[0];   // (2*NC*NS, DD) f32
    float* cls = (float*)d_ws;                  // NC per-class losses
    float* out = (float*)d_out;                 // 1 float
    ccl_two_class<<<NC / 2, 512, 0, stream>>>(emb, cls);
    ccl_reduce<<<1, 64, 0, stream>>>(cls, out);
}

// Round 13
// 26.546 us; speedup vs baseline: 1.0253x; 1.0253x over previous
//
#include <hip/hip_runtime.h>

#define NC 1024
#define NS 32
#define DD 512
#define MARGIN 0.3f

// ===== R11 (best: 26.6 us) — verbatim revert from the R12 experiment =====
//
// Kernel 1: one block per class, 512 threads (8 waves). Wave w owns float4
// columns [w*16, w*16+16); within the wave, lane l = g*16 + c16 owns rows
// s = 4j+g (j<8) of float4 column col4 = w*16 + c16. All 32 rows of each
// column live in ONE wave -> the anchor combine is intra-wave shfl_xor(16,32):
// no barrier, no LDS until the final tail combine. Each wave proceeds as soon
// as its own 16 dwordx4 loads return (no block-wide stall on slowest wave).
//
// Codegen rules (R3-R8, hard-won): literal loop bounds only (SROA); NO
// atomics of any spelling in this kernel (scratch demotion / coherent-point
// serialization); separate reduce kernel.
__global__ __launch_bounds__(512) void ccl_per_class(const float* __restrict__ emb,
                                                     float* __restrict__ cls) {
    const int c = blockIdx.x;
    const int t = threadIdx.x;
    const int w = t >> 6;
    const int l = t & 63;
    const int g = l >> 4;
    const int c16 = l & 15;
    const int col4 = w * 16 + c16;
    const float4* posv = (const float4*)(emb + (size_t)c * (2 * NS * DD));
    const float4* negv = posv + NS * DD / 4;

    __shared__ float s_wap[8][4][8];  // [wave][g][j] sample partials (ap)
    __shared__ float s_wnd[8][4][8];  // [wave][g][j] sample partials (nd)

    // ---- load 8 pos + 8 neg float4 rows of this column (rows s = 4j+g) ----
    float4 p[8], n[8];
#pragma unroll
    for (int j = 0; j < 8; ++j) p[j] = posv[(4 * j + g) * (DD / 4) + col4];
#pragma unroll
    for (int j = 0; j < 8; ++j) n[j] = negv[(4 * j + g) * (DD / 4) + col4];

    // ---- anchor: 8-row local sum, then fold the 4 g-groups intra-wave ----
    float4 a = p[0];
#pragma unroll
    for (int j = 1; j < 8; ++j) {
        a.x += p[j].x; a.y += p[j].y; a.z += p[j].z; a.w += p[j].w;
    }
    a.x += __shfl_xor(a.x, 16); a.y += __shfl_xor(a.y, 16);
    a.z += __shfl_xor(a.z, 16); a.w += __shfl_xor(a.w, 16);
    a.x += __shfl_xor(a.x, 32); a.y += __shfl_xor(a.y, 32);
    a.z += __shfl_xor(a.z, 32); a.w += __shfl_xor(a.w, 32);
    a.x *= (1.f / NS); a.y *= (1.f / NS); a.z *= (1.f / NS); a.w *= (1.f / NS);

    // ---- per-(sample, column-quad) squared-diff partials ----
    float apc[8], ndc[8];
#pragma unroll
    for (int j = 0; j < 8; ++j) {
        float dx = p[j].x - a.x, dy = p[j].y - a.y, dz = p[j].z - a.z, dw = p[j].w - a.w;
        apc[j] = dx * dx + dy * dy + dz * dz + dw * dw;
        dx = n[j].x - a.x; dy = n[j].y - a.y; dz = n[j].z - a.z; dw = n[j].w - a.w;
        ndc[j] = dx * dx + dy * dy + dz * dz + dw * dw;
    }

    // ---- halving butterfly across the 16 lanes of this g-group ----
    // Step mask m pairs lanes l, l^m; the (l&m)-set lane keeps the hi half.
#define BSTEP(arr, m, half)                                        \
    {                                                              \
        _Pragma("unroll")                                          \
        for (int i = 0; i < (half); ++i) {                         \
            float lo = arr[i], hi = arr[i + (half)];               \
            float send = (l & (m)) ? lo : hi;                      \
            float recv = __shfl_xor(send, (m));                    \
            arr[i] = (l & (m)) ? (hi + recv) : (lo + recv);        \
        }                                                          \
    }
    BSTEP(apc, 1, 4) BSTEP(apc, 2, 2) BSTEP(apc, 4, 1)
    BSTEP(ndc, 1, 4) BSTEP(ndc, 2, 2) BSTEP(ndc, 4, 1)
#undef BSTEP
    // lane holds element j = bitrev3(l&7) summed over its 8-lane subgroup;
    // fold the two subgroups of the 16-lane g-group:
    float rap = apc[0] + __shfl_xor(apc[0], 8);
    float rnd = ndc[0] + __shfl_xor(ndc[0], 8);
    if ((l & 8) == 0) {
        const int jm = ((l & 1) << 2) | (l & 2) | ((l & 4) >> 2);
        s_wap[w][g][jm] = rap;
        s_wnd[w][g][jm] = rnd;
    }
    __syncthreads();

    // ---- combine 8 waves; min + hinge in lanes 0-31 of wave 0 ----
    // Sample s = 4j+g -> g = s&3, j = s>>2.
    if (t < NS) {
        const int sg = t & 3, sj = t >> 2;
        float ap = 0.f, nd = 0.f;
#pragma unroll
        for (int k = 0; k < 8; ++k) {
            ap += s_wap[k][sg][sj];
            nd += s_wnd[k][sg][sj];
        }
        float an = nd;
#pragma unroll
        for (int m = 1; m < 32; m <<= 1) an = fminf(an, __shfl_xor(an, m));
        float hl = fmaxf(ap - an + MARGIN, 0.f);
#pragma unroll
        for (int m = 1; m < 32; m <<= 1) hl += __shfl_xor(hl, m);
        if (t == 0) cls[c] = hl;
    }
}

// Kernel 2: single-wave deterministic mean of the 1024 class losses.
// 64 threads, 4 float4 loads each, pure shuffle reduce -- no LDS, no barrier.
__global__ __launch_bounds__(64) void ccl_reduce(const float* __restrict__ class_loss,
                                                 float* __restrict__ out) {
    const int t = threadIdx.x;
    const float4* v4 = (const float4*)class_loss;  // 256 float4
    float4 x0 = v4[t], x1 = v4[t + 64], x2 = v4[t + 128], x3 = v4[t + 192];
    float v = (x0.x + x0.y + x0.z + x0.w) + (x1.x + x1.y + x1.z + x1.w) +
              (x2.x + x2.y + x2.z + x2.w) + (x3.x + x3.y + x3.z + x3.w);
#pragma unroll
    for (int m = 1; m < 64; m <<= 1) v += __shfl_xor(v, m);
    if (t == 0) out[0] = v * (1.f / NC);
}

extern "C" void kernel_launch(void* const* d_in, const int* in_sizes, int n_in,
                              void* d_out, int out_size, void* d_ws, size_t ws_size,
                              hipStream_t stream) {
    const float* emb = (const float*)d_in[0];   // (2*NC*NS, DD) f32
    float* cls = (float*)d_ws;                  // NC per-class losses
    float* out = (float*)d_out;                 // 1 float
    ccl_per_class<<<NC, 512, 0, stream>>>(emb, cls);
    ccl_reduce<<<1, 64, 0, stream>>>(cls, out);
}